// Round 1
// baseline (1176.895 us; speedup 1.0000x reference)
//
#include <hip/hip_runtime.h>
#include <math.h>

#define N_NODES 50000
#define N_EDGES 1600000
#define IN_CH   512
#define OUT_CH  48

// ---------------- Kernel 1: xw = features @ weight ----------------
// One thread per (row, 4-column group). 50000 * 12 = 600000 threads.
// features row read as float4 (broadcast across the 12 threads of a row via L1),
// weight read as float4, coalesced across adjacent threads (consecutive cg).
__global__ void gemm_xw(const float* __restrict__ f,
                        const float* __restrict__ w,
                        float* __restrict__ xw) {
    int idx = blockIdx.x * blockDim.x + threadIdx.x;
    const int total = N_NODES * (OUT_CH / 4);
    if (idx >= total) return;
    int row = idx / (OUT_CH / 4);
    int cg  = idx % (OUT_CH / 4);

    const float4* f4 = reinterpret_cast<const float4*>(f + (size_t)row * IN_CH);
    const float*  wc = w + cg * 4;

    float4 acc = make_float4(0.f, 0.f, 0.f, 0.f);
    #pragma unroll 4
    for (int k4 = 0; k4 < IN_CH / 4; ++k4) {
        float4 fv = f4[k4];
        float4 w0 = *reinterpret_cast<const float4*>(wc + (size_t)(4 * k4 + 0) * OUT_CH);
        float4 w1 = *reinterpret_cast<const float4*>(wc + (size_t)(4 * k4 + 1) * OUT_CH);
        float4 w2 = *reinterpret_cast<const float4*>(wc + (size_t)(4 * k4 + 2) * OUT_CH);
        float4 w3 = *reinterpret_cast<const float4*>(wc + (size_t)(4 * k4 + 3) * OUT_CH);
        acc.x = fmaf(fv.x, w0.x, acc.x); acc.y = fmaf(fv.x, w0.y, acc.y);
        acc.z = fmaf(fv.x, w0.z, acc.z); acc.w = fmaf(fv.x, w0.w, acc.w);
        acc.x = fmaf(fv.y, w1.x, acc.x); acc.y = fmaf(fv.y, w1.y, acc.y);
        acc.z = fmaf(fv.y, w1.z, acc.z); acc.w = fmaf(fv.y, w1.w, acc.w);
        acc.x = fmaf(fv.z, w2.x, acc.x); acc.y = fmaf(fv.z, w2.y, acc.y);
        acc.z = fmaf(fv.z, w2.z, acc.z); acc.w = fmaf(fv.z, w2.w, acc.w);
        acc.x = fmaf(fv.w, w3.x, acc.x); acc.y = fmaf(fv.w, w3.y, acc.y);
        acc.z = fmaf(fv.w, w3.z, acc.z); acc.w = fmaf(fv.w, w3.w, acc.w);
    }
    *reinterpret_cast<float4*>(xw + (size_t)row * OUT_CH + cg * 4) = acc;
}

// ---------------- Kernel 2: scatter-add messages into d_out ----------------
// One thread per (edge, 4-column group). For a fixed edge, its 12 threads read
// a contiguous 192B row of xw (coalesced) and atomically add into a contiguous
// 192B row of aggr.
__global__ void scatter_add(const int* __restrict__ src,
                            const int* __restrict__ dst,
                            const float* __restrict__ ew,
                            const float* __restrict__ xw,
                            float* __restrict__ aggr) {
    int idx = blockIdx.x * blockDim.x + threadIdx.x;
    const int total = N_EDGES * (OUT_CH / 4);
    if (idx >= total) return;
    int e  = idx / (OUT_CH / 4);
    int cg = idx % (OUT_CH / 4);

    int s = src[e];
    int d = dst[e];
    float wgt = ew[e];

    float4 v = *reinterpret_cast<const float4*>(xw + (size_t)s * OUT_CH + cg * 4);
    float* o = aggr + (size_t)d * OUT_CH + cg * 4;
    atomicAdd(o + 0, wgt * v.x);
    atomicAdd(o + 1, wgt * v.y);
    atomicAdd(o + 2, wgt * v.z);
    atomicAdd(o + 3, wgt * v.w);
}

// ---------------- Kernel 3: z = aggr + bias; out = log_softmax(z) ----------------
// One thread per row, in-place on d_out.
__global__ void log_softmax_rows(float* __restrict__ z,
                                 const float* __restrict__ bias) {
    int row = blockIdx.x * blockDim.x + threadIdx.x;
    if (row >= N_NODES) return;

    float v[OUT_CH];
    float4* zp = reinterpret_cast<float4*>(z + (size_t)row * OUT_CH);
    const float4* bp = reinterpret_cast<const float4*>(bias);

    float m = -INFINITY;
    #pragma unroll
    for (int g = 0; g < OUT_CH / 4; ++g) {
        float4 t = zp[g];
        float4 b = bp[g];
        t.x += b.x; t.y += b.y; t.z += b.z; t.w += b.w;
        v[4 * g + 0] = t.x; v[4 * g + 1] = t.y;
        v[4 * g + 2] = t.z; v[4 * g + 3] = t.w;
        m = fmaxf(m, fmaxf(fmaxf(t.x, t.y), fmaxf(t.z, t.w)));
    }
    float s = 0.f;
    #pragma unroll
    for (int c = 0; c < OUT_CH; ++c) s += expf(v[c] - m);
    float lse = logf(s) + m;
    #pragma unroll
    for (int g = 0; g < OUT_CH / 4; ++g) {
        float4 t;
        t.x = v[4 * g + 0] - lse; t.y = v[4 * g + 1] - lse;
        t.z = v[4 * g + 2] - lse; t.w = v[4 * g + 3] - lse;
        zp[g] = t;
    }
}

extern "C" void kernel_launch(void* const* d_in, const int* in_sizes, int n_in,
                              void* d_out, int out_size, void* d_ws, size_t ws_size,
                              hipStream_t stream) {
    // Inputs (setup_inputs order): edge_index [2,E] int, features [N,512] f32,
    // edge_weights [E] f32, weight [512,48] f32, bias [48] f32.
    const int*   edge_index = (const int*)d_in[0];
    const float* features   = (const float*)d_in[1];
    const float* eweights   = (const float*)d_in[2];
    const float* weight     = (const float*)d_in[3];
    const float* bias       = (const float*)d_in[4];

    const int* src = edge_index;            // edge_index[0, :]
    const int* dst = edge_index + N_EDGES;  // edge_index[1, :]

    float* out = (float*)d_out;             // [N, 48] — used as the aggregation buffer
    float* xw  = (float*)d_ws;              // [N, 48] projected features

    // Zero the aggregation buffer (harness poisons d_out; atomics need zeros).
    hipMemsetAsync(d_out, 0, (size_t)N_NODES * OUT_CH * sizeof(float), stream);

    // 1) xw = features @ weight
    {
        int total = N_NODES * (OUT_CH / 4);
        int block = 256;
        int grid  = (total + block - 1) / block;
        gemm_xw<<<grid, block, 0, stream>>>(features, weight, xw);
    }
    // 2) scatter-add weighted messages
    {
        int total = N_EDGES * (OUT_CH / 4);
        int block = 256;
        int grid  = (total + block - 1) / block;
        scatter_add<<<grid, block, 0, stream>>>(src, dst, eweights, xw, out);
    }
    // 3) bias + log_softmax, in place
    {
        int block = 256;
        int grid  = (N_NODES + block - 1) / block;
        log_softmax_rows<<<grid, block, 0, stream>>>(out, bias);
    }
}